// Round 5
// baseline (799.430 us; speedup 1.0000x reference)
//
#include <hip/hip_runtime.h>
#include <hip/hip_bf16.h>
#include <stdint.h>

typedef __attribute__((ext_vector_type(8))) short bf16x8;
typedef __attribute__((ext_vector_type(4))) float f32x4;
typedef unsigned long long ull;

__device__ __forceinline__ void load_lds16(const void* g, void* l){
  __builtin_amdgcn_global_load_lds((const __attribute__((address_space(1))) void*)g,
                                   (__attribute__((address_space(3))) void*)l, 16, 0, 0);
}

__device__ __forceinline__ float bf2f(unsigned int u){
  union { unsigned int i; float f; } x; x.i = u << 16; return x.f;
}
__device__ __forceinline__ unsigned short f2bf(float f){
  __hip_bfloat16 h = __float2bfloat16(f);
  unsigned short u;
  __builtin_memcpy(&u, &h, 2);
  return u;
}

// ---------- conversions ----------
__global__ void cvt_x_kernel(const float4* __restrict__ in, ushort4* __restrict__ out, int n4){
  int i = blockIdx.x*256 + threadIdx.x;
  if (i < n4){
    float4 v = in[i];
    ushort4 o;
    o.x = f2bf(v.x); o.y = f2bf(v.y); o.z = f2bf(v.z); o.w = f2bf(v.w);
    out[i] = o;
  }
}

// Wt[n][k] = bf16(W[k][n]) for n < N, 0 for N <= n < Npad
__global__ void wtrans_kernel(const float* __restrict__ W, unsigned short* __restrict__ Wt,
                              int K, int N, int Npad){
  int idx = blockIdx.x*256 + threadIdx.x;
  if (idx >= Npad*K) return;
  int nn = idx / K, kk = idx - nn*K;
  float v = (nn < N) ? W[(size_t)kk*N + nn] : 0.f;
  Wt[idx] = f2bf(v);
}

// ---------- graph preprocessing ----------
__global__ void hist_kernel(const int* __restrict__ col, int E, int* __restrict__ deg){
  int i = blockIdx.x*256 + threadIdx.x;
  if (i < E) atomicAdd(&deg[col[i]], 1);
}

__global__ void dis_kernel(const int* __restrict__ d1, const int* __restrict__ d2,
                           float* __restrict__ s1, float* __restrict__ s2, int n){
  int i = blockIdx.x*256 + threadIdx.x;
  if (i < n){
    int a = d1[i]; s1[i] = (a > 0) ? (1.0f/sqrtf((float)a)) : 0.f;
    int b = d2[i]; s2[i] = (b > 0) ? (1.0f/sqrtf((float)b)) : 0.f;
  }
}

// scans run on PADDED degrees: pdeg = (deg+7)&~7  (8-edge multiples per node)
__global__ void scan1_kernel(const int* __restrict__ deg1, const int* __restrict__ deg2,
                             int* __restrict__ off1, int* __restrict__ off2,
                             int* __restrict__ bsum, int n){
  __shared__ int s[1024];
  int set = blockIdx.y;
  const int* deg = set ? deg2 : deg1;
  int* off = set ? off2 : off1;
  int tid = threadIdx.x;
  int i = blockIdx.x*1024 + tid;
  int v = (i < n) ? ((deg[i] + 7) & ~7) : 0;
  s[tid] = v;
  __syncthreads();
  for (int o = 1; o < 1024; o <<= 1){
    int t = (tid >= o) ? s[tid - o] : 0;
    __syncthreads();
    s[tid] += t;
    __syncthreads();
  }
  if (i < n) off[i] = s[tid];          // inclusive, chunk-local (fixed in pass 3)
  if (tid == 1023) bsum[set*64 + blockIdx.x] = s[1023];
}

__global__ void scan2_kernel(const int* __restrict__ bsum, int* __restrict__ bbase,
                             int nch, int* __restrict__ off1, int* __restrict__ off2, int n){
  int set = threadIdx.x;
  if (set < 2){
    int run = 0;
    for (int j = 0; j < nch; ++j){ bbase[set*64 + j] = run; run += bsum[set*64 + j]; }
    (set ? off2 : off1)[n] = run;      // total padded edge count
  }
}

__global__ void scan3_kernel(const int* __restrict__ deg1, const int* __restrict__ deg2,
                             int* __restrict__ off1, int* __restrict__ off2,
                             const int* __restrict__ bbase, int n){
  int set = blockIdx.y;
  const int* deg = set ? deg2 : deg1;
  int* off = set ? off2 : off1;
  int i = blockIdx.x*1024 + threadIdx.x;
  if (i < n){
    int e = off[i] + bbase[set*64 + blockIdx.x];
    off[i] = e - ((deg[i] + 7) & ~7);  // exclusive global padded prefix
  }
}

// pack {row, dis[row]} per edge, bucketed by destination col (pad slots stay {0,0})
__global__ void scatter_kernel(const int* __restrict__ ei, int E,
                               const int* __restrict__ off, int* __restrict__ cur,
                               const float* __restrict__ dis, int2* __restrict__ csr){
  int e = blockIdx.x*256 + threadIdx.x;
  if (e >= E) return;
  int r = ei[e], c = ei[E + e];
  int p = off[c] + atomicAdd(&cur[c], 1);
  int2 rec; rec.x = r; rec.y = __float_as_int(dis[r]);
  csr[p] = rec;
}

// ---------- GCN aggregation, feature-chunked ----------
// out[c][f] = dis[c] * sum_e dis[r]*hw[r][f] + b[f], computed for a 32-feature
// chunk per launch. hw is stored chunk-major: [4][ntab][32] bf16, so each pass
// gathers 64B rows from a 3.2MB slab that fits per-XCD L2 (miss lat ~200cy vs
// ~500 for L3). Lane scheme: quarter-wave q handles edge 4t+q; lane covers 2
// features (4B gather). CSR read = 32B-contiguous broadcast load per step.
// Cross-quarter reduce via 2x shfl_xor. Padding to 8-edge multiples => steps even.
__global__ __launch_bounds__(256) void conv_kernel(
    const int* __restrict__ off1, const ull* __restrict__ csr1, const float* __restrict__ dis1,
    const int* __restrict__ off2, const ull* __restrict__ csr2, const float* __restrict__ dis2,
    const unsigned short* __restrict__ hwtab,   // [4][ntab][32] bf16
    const float* __restrict__ bias, unsigned short* __restrict__ outR,
    int n, int ntab, int chunk)
{
  const int set = blockIdx.y;
  const int* __restrict__ off = set ? off2 : off1;
  const float* __restrict__ dis = set ? dis2 : dis1;
  const ull* __restrict__ csrq = set ? csr2 : csr1;
  const int col_ofs = set ? 128 : 0;

  int wv = blockIdx.x*4 + (threadIdx.x >> 6);
  if (wv >= n) return;
  const int l = threadIdx.x & 63;
  const int q4 = l >> 4;        // quarter index: which edge of the 4-edge step
  const int lf = l & 15;        // feature-pair index within the 32-feat chunk
  const int s = off[wv], e = off[wv+1];
  const int nsteps = (e - s) >> 2;            // 4 edges/step; padded => even
  const ull* cp = csrq + s + q4;
  const unsigned* __restrict__ slab =
      (const unsigned*)(hwtab + (size_t)chunk * ntab * 32);

  float ax = 0.f, ay = 0.f;
  int t = 0;
  // 4-step (16-edge) main loop: 4 csr loads + 4 gathers in flight per wave
  for (; t + 4 <= nsteps; t += 4){
    ull q0 = __builtin_nontemporal_load(cp + (t+0)*4);
    ull q1 = __builtin_nontemporal_load(cp + (t+1)*4);
    ull q2 = __builtin_nontemporal_load(cp + (t+2)*4);
    ull q3 = __builtin_nontemporal_load(cp + (t+3)*4);
    unsigned v0 = slab[(size_t)(unsigned)q0 * 16 + lf];
    unsigned v1 = slab[(size_t)(unsigned)q1 * 16 + lf];
    unsigned v2 = slab[(size_t)(unsigned)q2 * 16 + lf];
    unsigned v3 = slab[(size_t)(unsigned)q3 * 16 + lf];
    float d0 = __int_as_float((unsigned)(q0 >> 32));
    float d1 = __int_as_float((unsigned)(q1 >> 32));
    float d2 = __int_as_float((unsigned)(q2 >> 32));
    float d3 = __int_as_float((unsigned)(q3 >> 32));
    ax = fmaf(d0, bf2f(v0 & 0xffffu), ax); ay = fmaf(d0, bf2f(v0 >> 16), ay);
    ax = fmaf(d1, bf2f(v1 & 0xffffu), ax); ay = fmaf(d1, bf2f(v1 >> 16), ay);
    ax = fmaf(d2, bf2f(v2 & 0xffffu), ax); ay = fmaf(d2, bf2f(v2 >> 16), ay);
    ax = fmaf(d3, bf2f(v3 & 0xffffu), ax); ay = fmaf(d3, bf2f(v3 >> 16), ay);
  }
  for (; t < nsteps; ++t){
    ull q0 = __builtin_nontemporal_load(cp + t*4);
    unsigned v0 = slab[(size_t)(unsigned)q0 * 16 + lf];
    float d0 = __int_as_float((unsigned)(q0 >> 32));
    ax = fmaf(d0, bf2f(v0 & 0xffffu), ax); ay = fmaf(d0, bf2f(v0 >> 16), ay);
  }

  // reduce the 4 quarter-wave partials (edges t*4+q) to quarter 0
  ax += __shfl_xor(ax, 16, 64); ay += __shfl_xor(ay, 16, 64);
  ax += __shfl_xor(ax, 32, 64); ay += __shfl_xor(ay, 32, 64);

  if (q4 == 0){
    const float dc = dis[wv];
    float b0 = bias[chunk*32 + lf*2 + 0];
    float b1 = bias[chunk*32 + lf*2 + 1];
    unsigned ov = (unsigned)f2bf(fmaf(dc, ax, b0)) |
                  ((unsigned)f2bf(fmaf(dc, ay, b1)) << 16);
    __builtin_nontemporal_store(ov,
        (unsigned*)&outR[(size_t)wv*256 + col_ofs + chunk*32 + lf*2]);
  }
}

// ---------- bf16 MFMA GEMM, m97-style 2-barrier loop ----------
// A [M x K] bf16 row-major (lda), Bt = B^T stored [BN_total x K] bf16.
// EPI 0: plain bf16 store; EPI 1: +bias, relu, bf16 store;
// EPI 2: A = 3 slabs (h|R1|R2, lda=256 each), +bias, fused log_softmax, f32 store;
// EPI 3: chunk-major slab store [col>>5][row][col&31] (ldc = table row count).
template<int FM, int FN, int WGM, int WGN, int EPI>
__global__ __launch_bounds__(256, 2) void gemm_kernel(
    const unsigned short* __restrict__ A0, const unsigned short* __restrict__ A1,
    const unsigned short* __restrict__ A2,
    const unsigned short* __restrict__ Bt, const float* __restrict__ bias,
    void* __restrict__ Cout, int M, int K, int lda, int ldc)
{
  constexpr int BM = WGM*FM*16;
  constexpr int BN = WGN*FN*16;
  constexpr int BK = 32;
  static_assert(BM == 128, "staging assumes BM==128");
  __shared__ unsigned short As[BM][BK];
  __shared__ unsigned short Bs[BN][BK];
  const int tid = threadIdx.x;
  const int w = tid >> 6, l = tid & 63;
  const int wr = w / WGN, wc = w % WGN;
  const int m0 = blockIdx.x*BM, n0 = blockIdx.y*BN;
  f32x4 acc[FM][FN] = {};
  const int nsteps = K / BK;
  for (int s = 0; s < nsteps; ++s){
    const int k0 = s*BK;
    const unsigned short* Asrc = A0;
    int kin = k0;
    if constexpr (EPI == 2){
      int slab = k0 >> 8;
      Asrc = (slab == 0) ? A0 : ((slab == 1) ? A1 : A2);
      kin = k0 & 255;
    }
    __syncthreads();
    #pragma unroll
    for (int j = 0; j < 2; ++j){           // A: 8KB = 2 x 4KB issues
      int idx = j*256 + tid;
      int row = idx >> 2, kq = idx & 3;
      int rg = m0 + row; rg = (rg < M) ? rg : (M - 1);
      load_lds16(Asrc + (size_t)rg*lda + kin + kq*8,
                 ((char*)&As[0][0]) + (size_t)(j*256 + w*64)*16);
    }
    #pragma unroll
    for (int j = 0; j < BN/64; ++j){       // Bt: [n][k] layout, same pattern as A
      int idx = j*256 + tid;
      int row = idx >> 2, kq = idx & 3;
      load_lds16(Bt + (size_t)(n0 + row)*K + k0 + kq*8,
                 ((char*)&Bs[0][0]) + (size_t)(j*256 + w*64)*16);
    }
    __syncthreads();
    bf16x8 af[FM], bfr[FN];
    const int kofs = (l >> 4)*8, l16 = l & 15;
    #pragma unroll
    for (int mi = 0; mi < FM; ++mi)
      af[mi] = *(const bf16x8*)&As[wr*FM*16 + mi*16 + l16][kofs];
    #pragma unroll
    for (int ni = 0; ni < FN; ++ni)
      bfr[ni] = *(const bf16x8*)&Bs[wc*FN*16 + ni*16 + l16][kofs];
    #pragma unroll
    for (int mi = 0; mi < FM; ++mi)
      #pragma unroll
      for (int ni = 0; ni < FN; ++ni)
        acc[mi][ni] = __builtin_amdgcn_mfma_f32_16x16x32_bf16(af[mi], bfr[ni], acc[mi][ni], 0, 0, 0);
  }
  const int lg = l >> 4, lc = l & 15;
  if constexpr (EPI == 2){
    float* O = (float*)Cout;
    #pragma unroll
    for (int mi = 0; mi < FM; ++mi){
      #pragma unroll
      for (int i = 0; i < 4; ++i){
        int row = m0 + wr*FM*16 + mi*16 + lg*4 + i;
        float v[FN];
        float mx = -1e30f;
        #pragma unroll
        for (int ni = 0; ni < FN; ++ni){
          int col = ni*16 + lc;                       // WGN==1, n0==0
          v[ni] = acc[mi][ni][i] + ((col < 40) ? bias[col] : 0.f);
          if (col < 40) mx = fmaxf(mx, v[ni]);
        }
        #pragma unroll
        for (int d = 1; d < 16; d <<= 1) mx = fmaxf(mx, __shfl_xor(mx, d, 64));
        float se = 0.f;
        #pragma unroll
        for (int ni = 0; ni < FN; ++ni){
          int col = ni*16 + lc;
          if (col < 40) se += expf(v[ni] - mx);
        }
        #pragma unroll
        for (int d = 1; d < 16; d <<= 1) se += __shfl_xor(se, d, 64);
        float lse = logf(se);
        if (row < M){
          #pragma unroll
          for (int ni = 0; ni < FN; ++ni){
            int col = ni*16 + lc;
            if (col < 40) O[(size_t)row*40 + col] = v[ni] - mx - lse;
          }
        }
      }
    }
  } else {
    unsigned short* C = (unsigned short*)Cout;
    #pragma unroll
    for (int mi = 0; mi < FM; ++mi){
      #pragma unroll
      for (int i = 0; i < 4; ++i){
        int row = m0 + wr*FM*16 + mi*16 + lg*4 + i;
        if (row >= M) continue;
        #pragma unroll
        for (int ni = 0; ni < FN; ++ni){
          int col = n0 + wc*FN*16 + ni*16 + lc;
          float vv = acc[mi][ni][i];
          if constexpr (EPI == 1){ vv += bias[col]; vv = fmaxf(vv, 0.f); }
          if constexpr (EPI == 3){
            C[((size_t)(col >> 5)*ldc + row)*32 + (col & 31)] = f2bf(vv);
          } else {
            C[(size_t)row*ldc + col] = f2bf(vv);
          }
        }
      }
    }
  }
}

extern "C" void kernel_launch(void* const* d_in, const int* in_sizes, int n_in,
                              void* d_out, int out_size, void* d_ws, size_t ws_size,
                              hipStream_t stream)
{
  (void)n_in; (void)out_size;
  const float* x      = (const float*)d_in[0];
  const int*   ei1    = (const int*)d_in[1];
  const int*   ei2    = (const int*)d_in[2];
  const float* W_lin1 = (const float*)d_in[3];
  const float* b_lin1 = (const float*)d_in[4];
  const float* W_c1   = (const float*)d_in[5];
  const float* b_c1   = (const float*)d_in[6];
  const float* W_c2   = (const float*)d_in[7];
  const float* b_c2   = (const float*)d_in[8];
  const float* W_lin2 = (const float*)d_in[9];
  const float* b_lin2 = (const float*)d_in[10];

  const int N  = in_sizes[0] / 512;
  const int E1 = in_sizes[1] / 2;
  const int E2 = in_sizes[2] / 2;

  char* base = (char*)d_ws;
  size_t off = 0;
  auto alloc = [&](size_t bytes) -> char* {
    off = (off + 255) & ~(size_t)255;
    char* r = base + off;
    off += bytes;
    return r;
  };
  // padded-CSR capacities (pad <= 7 per node, + slack)
  const size_t cap1 = (size_t)E1 + 8*(size_t)N + 64;
  const size_t cap2 = (size_t)E2 + 8*(size_t)N + 64;

  unsigned short* xb   = (unsigned short*)alloc((size_t)N*512*2);  // reused as CSR after GEMM1
  unsigned short* h    = (unsigned short*)alloc((size_t)N*256*2);
  unsigned short* hw   = (unsigned short*)alloc((size_t)N*128*2);  // chunk-major [4][N][32]
  unsigned short* R1   = (unsigned short*)alloc((size_t)N*256*2);
  unsigned short* R2   = (unsigned short*)alloc((size_t)N*256*2);
  unsigned short* Wt1  = (unsigned short*)alloc((size_t)256*512*2);
  unsigned short* Wtc1 = (unsigned short*)alloc((size_t)128*256*2);
  unsigned short* Wtc2 = (unsigned short*)alloc((size_t)128*256*2);
  unsigned short* Wtf  = (unsigned short*)alloc((size_t)64*768*2); // W_lin2^T padded to 64 cols
  int* degblk = (int*)alloc((size_t)4*N*4);
  int* deg1 = degblk, *deg2 = degblk + N, *cur1 = degblk + 2*N, *cur2 = degblk + 3*N;
  float* dis1 = (float*)alloc((size_t)N*4);
  float* dis2 = (float*)alloc((size_t)N*4);
  int* off1 = (int*)alloc((size_t)(N+1)*4);
  int* off2 = (int*)alloc((size_t)(N+1)*4);
  int* bsum  = (int*)alloc(128*4);
  int* bbase = (int*)alloc(128*4);
  // CSR aliases the xb slab (xb is dead after GEMM1; 51.2MB >= 26MB needed)
  ull* csr1 = (ull*)xb;
  ull* csr2 = csr1 + cap1;
  if (off > ws_size) return;   // workspace insufficient -> visible validation failure

  int mt = (N + 127)/128;
  int cb = (N + 3)/4;

  // --- dense front: x->bf16, weight transposes, GEMM1 (uses xb before CSR aliases it) ---
  cvt_x_kernel<<<(N*512/4 + 255)/256, 256, 0, stream>>>((const float4*)x, (ushort4*)xb, N*512/4);
  wtrans_kernel<<<(256*512 + 255)/256, 256, 0, stream>>>(W_lin1, Wt1, 512, 256, 256);
  wtrans_kernel<<<(128*256 + 255)/256, 256, 0, stream>>>(W_c1, Wtc1, 256, 128, 128);
  wtrans_kernel<<<(128*256 + 255)/256, 256, 0, stream>>>(W_c2, Wtc2, 256, 128, 128);
  wtrans_kernel<<<(64*768 + 255)/256, 256, 0, stream>>>(W_lin2, Wtf, 768, 40, 64);
  // h = relu(x @ W_lin1 + b)
  gemm_kernel<4,4,2,2,1><<<dim3(mt, 2), 256, 0, stream>>>(xb, nullptr, nullptr, Wt1, b_lin1, h, N, 512, 512, 256);

  // --- graph preprocessing (overwrites xb slab with padded CSR) ---
  (void)hipMemsetAsync(degblk, 0, (size_t)4*N*4, stream);
  (void)hipMemsetAsync(csr1, 0, (cap1 + cap2)*8, stream);
  hist_kernel<<<(E1 + 255)/256, 256, 0, stream>>>(ei1 + E1, E1, deg1);
  hist_kernel<<<(E2 + 255)/256, 256, 0, stream>>>(ei2 + E2, E2, deg2);
  dis_kernel<<<(N + 255)/256, 256, 0, stream>>>(deg1, deg2, dis1, dis2, N);
  int nch = (N + 1023)/1024;
  scan1_kernel<<<dim3(nch, 2), 1024, 0, stream>>>(deg1, deg2, off1, off2, bsum, N);
  scan2_kernel<<<1, 64, 0, stream>>>(bsum, bbase, nch, off1, off2, N);
  scan3_kernel<<<dim3(nch, 2), 1024, 0, stream>>>(deg1, deg2, off1, off2, bbase, N);
  scatter_kernel<<<(E1 + 255)/256, 256, 0, stream>>>(ei1, E1, off1, cur1, dis1, (int2*)csr1);
  scatter_kernel<<<(E2 + 255)/256, 256, 0, stream>>>(ei2, E2, off2, cur2, dis2, (int2*)csr2);

  // --- layer 1: hw1 = h @ W_c1 (chunk-major), then 4 feature-chunk conv passes ---
  gemm_kernel<4,4,2,2,3><<<dim3(mt, 1), 256, 0, stream>>>(h, nullptr, nullptr, Wtc1, nullptr, hw, N, 256, 256, N);
  for (int ch = 0; ch < 4; ++ch)
    conv_kernel<<<dim3(cb, 2), 256, 0, stream>>>(off1, csr1, dis1, off2, csr2, dis2,
                                                 hw, b_c1, R1, N, N, ch);
  // --- layer 2: hw2 = R1 @ W_c2 (chunk-major), 4 passes ---
  gemm_kernel<4,4,2,2,3><<<dim3(mt, 1), 256, 0, stream>>>(R1, nullptr, nullptr, Wtc2, nullptr, hw, N, 256, 256, N);
  for (int ch = 0; ch < 4; ++ch)
    conv_kernel<<<dim3(cb, 2), 256, 0, stream>>>(off1, csr1, dis1, off2, csr2, dis2,
                                                 hw, b_c2, R2, N, N, ch);
  // --- head: logits = [h|R1|R2] @ W_lin2 + b, fused log_softmax ---
  gemm_kernel<2,4,4,1,2><<<dim3(mt, 1), 256, 0, stream>>>(h, R1, R2, Wtf, b_lin2, d_out, N, 768, 256, 40);
}

// Round 6
// 478.004 us; speedup vs baseline: 1.6724x; 1.6724x over previous
//
#include <hip/hip_runtime.h>
#include <hip/hip_bf16.h>
#include <stdint.h>

typedef __attribute__((ext_vector_type(8))) short bf16x8;
typedef __attribute__((ext_vector_type(4))) float f32x4;
typedef __attribute__((ext_vector_type(2))) float f32x2;
typedef __attribute__((ext_vector_type(4))) unsigned int u32x4;
typedef unsigned long long ull;

__device__ __forceinline__ void load_lds16(const void* g, void* l){
  __builtin_amdgcn_global_load_lds((const __attribute__((address_space(1))) void*)g,
                                   (__attribute__((address_space(3))) void*)l, 16, 0, 0);
}

__device__ __forceinline__ float bf2f(unsigned int u){
  union { unsigned int i; float f; } x; x.i = u << 16; return x.f;
}
__device__ __forceinline__ unsigned short f2bf(float f){
  __hip_bfloat16 h = __float2bfloat16(f);
  unsigned short u;
  __builtin_memcpy(&u, &h, 2);
  return u;
}

// ---------- conversions ----------
__global__ void cvt_x_kernel(const float4* __restrict__ in, ushort4* __restrict__ out, int n4){
  int i = blockIdx.x*256 + threadIdx.x;
  if (i < n4){
    float4 v = in[i];
    ushort4 o;
    o.x = f2bf(v.x); o.y = f2bf(v.y); o.z = f2bf(v.z); o.w = f2bf(v.w);
    out[i] = o;
  }
}

// Wt[n][k] = bf16(W[k][n]) for n < N, 0 for N <= n < Npad
__global__ void wtrans_kernel(const float* __restrict__ W, unsigned short* __restrict__ Wt,
                              int K, int N, int Npad){
  int idx = blockIdx.x*256 + threadIdx.x;
  if (idx >= Npad*K) return;
  int nn = idx / K, kk = idx - nn*K;
  float v = (nn < N) ? W[(size_t)kk*N + nn] : 0.f;
  Wt[idx] = f2bf(v);
}

// ---------- graph preprocessing ----------
// fused histogram over both edge sets
__global__ void hist2_kernel(const int* __restrict__ ei1, int E1, int* __restrict__ deg1,
                             const int* __restrict__ ei2, int E2, int* __restrict__ deg2){
  int set = blockIdx.y;
  const int* col = set ? (ei2 + E2) : (ei1 + E1);
  int E = set ? E2 : E1;
  int* deg = set ? deg2 : deg1;
  int i = blockIdx.x*256 + threadIdx.x;
  if (i < E) atomicAdd(&deg[col[i]], 1);
}

__global__ void dis_kernel(const int* __restrict__ d1, const int* __restrict__ d2,
                           float* __restrict__ s1, float* __restrict__ s2, int n){
  int i = blockIdx.x*256 + threadIdx.x;
  if (i < n){
    int a = d1[i]; s1[i] = (a > 0) ? (1.0f/sqrtf((float)a)) : 0.f;
    int b = d2[i]; s2[i] = (b > 0) ? (1.0f/sqrtf((float)b)) : 0.f;
  }
}

// pad CSR capacity with row index n (points at the zeroed table row)
__global__ void fill_kernel(unsigned* __restrict__ csr, size_t cap, unsigned padrow){
  size_t i = (size_t)blockIdx.x*256 + threadIdx.x;
  if (i < cap) csr[i] = padrow;
}

// scans run on PADDED degrees: pdeg = (deg+7)&~7  (8-edge multiples per node)
__global__ void scan1_kernel(const int* __restrict__ deg1, const int* __restrict__ deg2,
                             int* __restrict__ off1, int* __restrict__ off2,
                             int* __restrict__ bsum, int n){
  __shared__ int s[1024];
  int set = blockIdx.y;
  const int* deg = set ? deg2 : deg1;
  int* off = set ? off2 : off1;
  int tid = threadIdx.x;
  int i = blockIdx.x*1024 + tid;
  int v = (i < n) ? ((deg[i] + 7) & ~7) : 0;
  s[tid] = v;
  __syncthreads();
  for (int o = 1; o < 1024; o <<= 1){
    int t = (tid >= o) ? s[tid - o] : 0;
    __syncthreads();
    s[tid] += t;
    __syncthreads();
  }
  if (i < n) off[i] = s[tid];          // inclusive, chunk-local (fixed in pass 3)
  if (tid == 1023) bsum[set*64 + blockIdx.x] = s[1023];
}

__global__ void scan2_kernel(const int* __restrict__ bsum, int* __restrict__ bbase,
                             int nch, int* __restrict__ off1, int* __restrict__ off2, int n){
  int set = threadIdx.x;
  if (set < 2){
    int run = 0;
    for (int j = 0; j < nch; ++j){ bbase[set*64 + j] = run; run += bsum[set*64 + j]; }
    (set ? off2 : off1)[n] = run;      // total padded edge count
  }
}

__global__ void scan3_kernel(const int* __restrict__ deg1, const int* __restrict__ deg2,
                             int* __restrict__ off1, int* __restrict__ off2,
                             const int* __restrict__ bbase, int n){
  int set = blockIdx.y;
  const int* deg = set ? deg2 : deg1;
  int* off = set ? off2 : off1;
  int i = blockIdx.x*1024 + threadIdx.x;
  if (i < n){
    int e = off[i] + bbase[set*64 + blockIdx.x];
    off[i] = e - ((deg[i] + 7) & ~7);  // exclusive global padded prefix
  }
}

// fused scatter over both edge sets: record = row index only (4B)
__global__ void scatter2_kernel(const int* __restrict__ ei1, int E1,
                                const int* __restrict__ off1, int* __restrict__ cur1,
                                unsigned* __restrict__ csr1,
                                const int* __restrict__ ei2, int E2,
                                const int* __restrict__ off2, int* __restrict__ cur2,
                                unsigned* __restrict__ csr2){
  int set = blockIdx.y;
  const int* ei = set ? ei2 : ei1;
  int E = set ? E2 : E1;
  const int* off = set ? off2 : off1;
  int* cur = set ? cur2 : cur1;
  unsigned* csr = set ? csr2 : csr1;
  int e = blockIdx.x*256 + threadIdx.x;
  if (e >= E) return;
  int r = ei[e], c = ei[E + e];
  int p = off[c] + atomicAdd(&cur[c], 1);
  csr[p] = (unsigned)r;
}

// ---------- GCN aggregation: out[c] = dis[c] * sum_e T_set[r] + b ----------
// T_set rows are PRE-SCALED by dis_set[r] and stored fp8 e4m3: 128B/row = 2 lines
// per edge (vs 4 at bf16) -> halves beyond-L2 line traffic at the MSHR wall.
// Half-wave h consumes edges 8b+4h..8b+4h+3 (one contiguous uint4 record load);
// lane covers 4 features (4B gather). 2-stage pipeline, padded CSR (pad row = n).
__global__ __launch_bounds__(256) void conv_kernel(
    const int* __restrict__ off1, const unsigned* __restrict__ csr1, const float* __restrict__ dis1,
    const int* __restrict__ off2, const unsigned* __restrict__ csr2, const float* __restrict__ dis2,
    const unsigned char* __restrict__ Tbase,   // [2][ntab][128] fp8
    const float* __restrict__ bias, unsigned short* __restrict__ outR,
    int n, int ntab)
{
  const int set = blockIdx.y;
  const int* __restrict__ off = set ? off2 : off1;
  const float* __restrict__ dis = set ? dis2 : dis1;
  const unsigned* __restrict__ csrq = set ? csr2 : csr1;
  const int col_ofs = set ? 128 : 0;
  const unsigned* __restrict__ tab =
      (const unsigned*)(Tbase + (size_t)set * ntab * 128);

  int wv = blockIdx.x*4 + (threadIdx.x >> 6);
  if (wv >= n) return;
  const int l = threadIdx.x & 63;
  const int half = l >> 5, lf = l & 31;
  const int s = off[wv], e = off[wv+1];
  const int nb = (e - s) >> 3;               // 8-edge batches (exact, padded)
  const unsigned* cp = csrq + s + half*4;    // this half's 4 records per batch

  float ax = 0.f, ay = 0.f, az = 0.f, aw = 0.f;

  if (nb > 0){
    u32x4 qa, qb;
    unsigned va0, va1, va2, va3, vb0, vb1, vb2, vb3;

#define LQ(q, B) q = __builtin_nontemporal_load((const u32x4*)(cp + (B)*8));
#define GATH(v, q) \
    v##0 = tab[(size_t)q.x * 32 + lf]; \
    v##1 = tab[(size_t)q.y * 32 + lf]; \
    v##2 = tab[(size_t)q.z * 32 + lf]; \
    v##3 = tab[(size_t)q.w * 32 + lf];
#define FMA1(v) { \
    f32x2 lo = __builtin_amdgcn_cvt_pk_f32_fp8((int)v, false); \
    f32x2 hi = __builtin_amdgcn_cvt_pk_f32_fp8((int)v, true);  \
    ax += lo.x; ay += lo.y; az += hi.x; aw += hi.y; }
#define FMAB(v) { FMA1(v##0) FMA1(v##1) FMA1(v##2) FMA1(v##3) }

    LQ(qa, 0)
    GATH(va, qa)
    LQ(qb, 1)
    int b = 0;
    while (b + 2 <= nb){
      LQ(qa, b + 2)              // speculative reads stay inside filled csr capacity
      GATH(vb, qb)
      FMAB(va)
      LQ(qb, b + 3)
      GATH(va, qa)               // may gather next node's rows / pad rows; unused unless valid
      FMAB(vb)
      b += 2;
    }
    if (b < nb) FMAB(va)
#undef LQ
#undef GATH
#undef FMA1
#undef FMAB
  }

  // combine the two half-wave partial sums
  ax += __shfl_xor(ax, 32, 64);
  ay += __shfl_xor(ay, 32, 64);
  az += __shfl_xor(az, 32, 64);
  aw += __shfl_xor(aw, 32, 64);

  if (half == 0){
    const float dc = dis[wv];
    float b0 = bias[lf*4 + 0], b1 = bias[lf*4 + 1];
    float b2 = bias[lf*4 + 2], b3 = bias[lf*4 + 3];
    ull ov = (ull)((unsigned)f2bf(fmaf(dc, ax, b0)) | ((unsigned)f2bf(fmaf(dc, ay, b1)) << 16))
           | ((ull)((unsigned)f2bf(fmaf(dc, az, b2)) | ((unsigned)f2bf(fmaf(dc, aw, b3)) << 16)) << 32);
    __builtin_nontemporal_store(ov, (ull*)&outR[(size_t)wv*256 + col_ofs + lf*4]);
  }
}

// ---------- bf16 MFMA GEMM, m97-style 2-barrier loop ----------
// A [M x K] bf16 row-major (lda), Bt = B^T stored [BN_total x K] bf16.
// EPI 0: plain bf16 store; EPI 1: +bias, relu, bf16 store;
// EPI 2: A = 3 slabs (h|R1|R2, lda=256 each), +bias, fused log_softmax, f32 store;
// EPI 4: dual fp8 table store T[set][row][col] = fp8(vv * dis_set[row]).
template<int FM, int FN, int WGM, int WGN, int EPI>
__global__ __launch_bounds__(256, 2) void gemm_kernel(
    const unsigned short* __restrict__ A0, const unsigned short* __restrict__ A1,
    const unsigned short* __restrict__ A2,
    const unsigned short* __restrict__ Bt, const float* __restrict__ bias,
    void* __restrict__ Cout, int M, int K, int lda, int ldc,
    const float* __restrict__ d1, const float* __restrict__ d2, int ntab)
{
  constexpr int BM = WGM*FM*16;
  constexpr int BN = WGN*FN*16;
  constexpr int BK = 32;
  static_assert(BM == 128, "staging assumes BM==128");
  __shared__ unsigned short As[BM][BK];
  __shared__ unsigned short Bs[BN][BK];
  const int tid = threadIdx.x;
  const int w = tid >> 6, l = tid & 63;
  const int wr = w / WGN, wc = w % WGN;
  const int m0 = blockIdx.x*BM, n0 = blockIdx.y*BN;
  f32x4 acc[FM][FN] = {};
  const int nsteps = K / BK;
  for (int s = 0; s < nsteps; ++s){
    const int k0 = s*BK;
    const unsigned short* Asrc = A0;
    int kin = k0;
    if constexpr (EPI == 2){
      int slab = k0 >> 8;
      Asrc = (slab == 0) ? A0 : ((slab == 1) ? A1 : A2);
      kin = k0 & 255;
    }
    __syncthreads();
    #pragma unroll
    for (int j = 0; j < 2; ++j){           // A: 8KB = 2 x 4KB issues
      int idx = j*256 + tid;
      int row = idx >> 2, kq = idx & 3;
      int rg = m0 + row; rg = (rg < M) ? rg : (M - 1);
      load_lds16(Asrc + (size_t)rg*lda + kin + kq*8,
                 ((char*)&As[0][0]) + (size_t)(j*256 + w*64)*16);
    }
    #pragma unroll
    for (int j = 0; j < BN/64; ++j){       // Bt: [n][k] layout, same pattern as A
      int idx = j*256 + tid;
      int row = idx >> 2, kq = idx & 3;
      load_lds16(Bt + (size_t)(n0 + row)*K + k0 + kq*8,
                 ((char*)&Bs[0][0]) + (size_t)(j*256 + w*64)*16);
    }
    __syncthreads();
    bf16x8 af[FM], bfr[FN];
    const int kofs = (l >> 4)*8, l16 = l & 15;
    #pragma unroll
    for (int mi = 0; mi < FM; ++mi)
      af[mi] = *(const bf16x8*)&As[wr*FM*16 + mi*16 + l16][kofs];
    #pragma unroll
    for (int ni = 0; ni < FN; ++ni)
      bfr[ni] = *(const bf16x8*)&Bs[wc*FN*16 + ni*16 + l16][kofs];
    #pragma unroll
    for (int mi = 0; mi < FM; ++mi)
      #pragma unroll
      for (int ni = 0; ni < FN; ++ni)
        acc[mi][ni] = __builtin_amdgcn_mfma_f32_16x16x32_bf16(af[mi], bfr[ni], acc[mi][ni], 0, 0, 0);
  }
  const int lg = l >> 4, lc = l & 15;
  if constexpr (EPI == 2){
    float* O = (float*)Cout;
    #pragma unroll
    for (int mi = 0; mi < FM; ++mi){
      #pragma unroll
      for (int i = 0; i < 4; ++i){
        int row = m0 + wr*FM*16 + mi*16 + lg*4 + i;
        float v[FN];
        float mx = -1e30f;
        #pragma unroll
        for (int ni = 0; ni < FN; ++ni){
          int col = ni*16 + lc;                       // WGN==1, n0==0
          v[ni] = acc[mi][ni][i] + ((col < 40) ? bias[col] : 0.f);
          if (col < 40) mx = fmaxf(mx, v[ni]);
        }
        #pragma unroll
        for (int d = 1; d < 16; d <<= 1) mx = fmaxf(mx, __shfl_xor(mx, d, 64));
        float se = 0.f;
        #pragma unroll
        for (int ni = 0; ni < FN; ++ni){
          int col = ni*16 + lc;
          if (col < 40) se += expf(v[ni] - mx);
        }
        #pragma unroll
        for (int d = 1; d < 16; d <<= 1) se += __shfl_xor(se, d, 64);
        float lse = logf(se);
        if (row < M){
          #pragma unroll
          for (int ni = 0; ni < FN; ++ni){
            int col = ni*16 + lc;
            if (col < 40) O[(size_t)row*40 + col] = v[ni] - mx - lse;
          }
        }
      }
    }
  } else if constexpr (EPI == 4){
    unsigned char* T = (unsigned char*)Cout;            // [2][ntab][128]
    #pragma unroll
    for (int mi = 0; mi < FM; ++mi){
      #pragma unroll
      for (int i = 0; i < 4; ++i){
        int row = m0 + wr*FM*16 + mi*16 + lg*4 + i;
        if (row >= M) continue;
        float s1 = d1[row], s2 = d2[row];
        #pragma unroll
        for (int ni = 0; ni < FN; ++ni){
          int col = n0 + wc*FN*16 + ni*16 + lc;        // [0,128)
          float vv = acc[mi][ni][i];
          unsigned p1 = (unsigned)__builtin_amdgcn_cvt_pk_fp8_f32(vv*s1, vv*s1, 0, false);
          unsigned p2 = (unsigned)__builtin_amdgcn_cvt_pk_fp8_f32(vv*s2, vv*s2, 0, false);
          T[(size_t)row*128 + col] = (unsigned char)(p1 & 0xff);
          T[((size_t)ntab + row)*128 + col] = (unsigned char)(p2 & 0xff);
        }
      }
    }
  } else {
    unsigned short* C = (unsigned short*)Cout;
    #pragma unroll
    for (int mi = 0; mi < FM; ++mi){
      #pragma unroll
      for (int i = 0; i < 4; ++i){
        int row = m0 + wr*FM*16 + mi*16 + lg*4 + i;
        if (row >= M) continue;
        #pragma unroll
        for (int ni = 0; ni < FN; ++ni){
          int col = n0 + wc*FN*16 + ni*16 + lc;
          float vv = acc[mi][ni][i];
          if constexpr (EPI == 1){ vv += bias[col]; vv = fmaxf(vv, 0.f); }
          C[(size_t)row*ldc + col] = f2bf(vv);
        }
      }
    }
  }
}

extern "C" void kernel_launch(void* const* d_in, const int* in_sizes, int n_in,
                              void* d_out, int out_size, void* d_ws, size_t ws_size,
                              hipStream_t stream)
{
  (void)n_in; (void)out_size;
  const float* x      = (const float*)d_in[0];
  const int*   ei1    = (const int*)d_in[1];
  const int*   ei2    = (const int*)d_in[2];
  const float* W_lin1 = (const float*)d_in[3];
  const float* b_lin1 = (const float*)d_in[4];
  const float* W_c1   = (const float*)d_in[5];
  const float* b_c1   = (const float*)d_in[6];
  const float* W_c2   = (const float*)d_in[7];
  const float* b_c2   = (const float*)d_in[8];
  const float* W_lin2 = (const float*)d_in[9];
  const float* b_lin2 = (const float*)d_in[10];

  const int N  = in_sizes[0] / 512;
  const int E1 = in_sizes[1] / 2;
  const int E2 = in_sizes[2] / 2;
  const int ntab = N + 1;                    // +1 zero row for pad edges

  char* base = (char*)d_ws;
  size_t off = 0;
  auto alloc = [&](size_t bytes) -> char* {
    off = (off + 255) & ~(size_t)255;
    char* r = base + off;
    off += bytes;
    return r;
  };
  // padded-CSR capacities in 4B records (pad <= 7 per node, + speculative slack)
  const size_t cap1 = (size_t)E1 + 8*(size_t)N + 64;
  const size_t cap2 = (size_t)E2 + 8*(size_t)N + 64;

  unsigned short* xb   = (unsigned short*)alloc((size_t)N*512*2);  // reused as CSR after GEMM1
  unsigned short* h    = (unsigned short*)alloc((size_t)N*256*2);
  unsigned char*  T    = (unsigned char*)alloc((size_t)2*ntab*128); // fp8 scaled tables
  unsigned short* R1   = (unsigned short*)alloc((size_t)N*256*2);
  unsigned short* R2   = (unsigned short*)alloc((size_t)N*256*2);
  unsigned short* Wt1  = (unsigned short*)alloc((size_t)256*512*2);
  unsigned short* Wtc1 = (unsigned short*)alloc((size_t)128*256*2);
  unsigned short* Wtc2 = (unsigned short*)alloc((size_t)128*256*2);
  unsigned short* Wtf  = (unsigned short*)alloc((size_t)64*768*2); // W_lin2^T padded to 64 cols
  int* degblk = (int*)alloc((size_t)4*N*4);
  int* deg1 = degblk, *deg2 = degblk + N, *cur1 = degblk + 2*N, *cur2 = degblk + 3*N;
  float* dis1 = (float*)alloc((size_t)N*4);
  float* dis2 = (float*)alloc((size_t)N*4);
  int* off1 = (int*)alloc((size_t)(N+1)*4);
  int* off2 = (int*)alloc((size_t)(N+1)*4);
  int* bsum  = (int*)alloc(128*4);
  int* bbase = (int*)alloc(128*4);
  // CSR aliases the xb slab (xb is dead after GEMM1; 51.2MB >= ~14MB needed)
  unsigned* csr1 = (unsigned*)xb;
  unsigned* csr2 = csr1 + cap1;
  if (off > ws_size) return;   // workspace insufficient -> visible validation failure

  int mt = (N + 127)/128;
  int cb = (N + 3)/4;

  // --- dense front: x->bf16, weight transposes, GEMM1 (uses xb before CSR aliases it) ---
  cvt_x_kernel<<<(N*512/4 + 255)/256, 256, 0, stream>>>((const float4*)x, (ushort4*)xb, N*512/4);
  wtrans_kernel<<<(256*512 + 255)/256, 256, 0, stream>>>(W_lin1, Wt1, 512, 256, 256);
  wtrans_kernel<<<(128*256 + 255)/256, 256, 0, stream>>>(W_c1, Wtc1, 256, 128, 128);
  wtrans_kernel<<<(128*256 + 255)/256, 256, 0, stream>>>(W_c2, Wtc2, 256, 128, 128);
  wtrans_kernel<<<(64*768 + 255)/256, 256, 0, stream>>>(W_lin2, Wtf, 768, 40, 64);
  // h = relu(x @ W_lin1 + b)
  gemm_kernel<4,4,2,2,1><<<dim3(mt, 2), 256, 0, stream>>>(xb, nullptr, nullptr, Wt1, b_lin1, h,
                                                          N, 512, 512, 256, nullptr, nullptr, 0);

  // --- graph preprocessing (overwrites xb slab with padded 4B-record CSR) ---
  (void)hipMemsetAsync(degblk, 0, (size_t)4*N*4, stream);
  (void)hipMemsetAsync(T + (size_t)N*128, 0, 128, stream);            // zero row, set 0
  (void)hipMemsetAsync(T + ((size_t)ntab + N)*128, 0, 128, stream);   // zero row, set 1
  fill_kernel<<<(int)((cap1 + cap2 + 255)/256), 256, 0, stream>>>(csr1, cap1 + cap2, (unsigned)N);
  hist2_kernel<<<dim3((E2 + 255)/256, 2), 256, 0, stream>>>(ei1, E1, deg1, ei2, E2, deg2);
  dis_kernel<<<(N + 255)/256, 256, 0, stream>>>(deg1, deg2, dis1, dis2, N);
  int nch = (N + 1023)/1024;
  scan1_kernel<<<dim3(nch, 2), 1024, 0, stream>>>(deg1, deg2, off1, off2, bsum, N);
  scan2_kernel<<<1, 64, 0, stream>>>(bsum, bbase, nch, off1, off2, N);
  scan3_kernel<<<dim3(nch, 2), 1024, 0, stream>>>(deg1, deg2, off1, off2, bbase, N);
  scatter2_kernel<<<dim3((E2 + 255)/256, 2), 256, 0, stream>>>(ei1, E1, off1, cur1, csr1,
                                                               ei2, E2, off2, cur2, csr2);

  // --- layer 1: T = fp8(dis_set[r] * (h @ W_c1)[r]), then one conv pass ---
  gemm_kernel<4,4,2,2,4><<<dim3(mt, 1), 256, 0, stream>>>(h, nullptr, nullptr, Wtc1, nullptr, T,
                                                          N, 256, 256, 0, dis1, dis2, ntab);
  conv_kernel<<<dim3(cb, 2), 256, 0, stream>>>(off1, csr1, dis1, off2, csr2, dis2,
                                               T, b_c1, R1, N, ntab);
  // --- layer 2: T = fp8(dis_set[r] * (R1 @ W_c2)[r]), conv ---
  gemm_kernel<4,4,2,2,4><<<dim3(mt, 1), 256, 0, stream>>>(R1, nullptr, nullptr, Wtc2, nullptr, T,
                                                          N, 256, 256, 0, dis1, dis2, ntab);
  conv_kernel<<<dim3(cb, 2), 256, 0, stream>>>(off1, csr1, dis1, off2, csr2, dis2,
                                               T, b_c2, R2, N, ntab);
  // --- head: logits = [h|R1|R2] @ W_lin2 + b, fused log_softmax ---
  gemm_kernel<2,4,4,1,2><<<dim3(mt, 1), 256, 0, stream>>>(h, R1, R2, Wtf, b_lin2, d_out,
                                                          N, 768, 256, 40, nullptr, nullptr, 0);
}